// Round 1
// 450.314 us; speedup vs baseline: 1.0087x; 1.0087x over previous
//
#include <hip/hip_runtime.h>
#include <hip/hip_bf16.h>

// UniPhyBlock: B=2,T=16,D=64,H=64,W=64. Outputs bf16; internal f32 accum,
// bf16 MFMA for conv / eig / dec / MLP. Input dtype auto-detected.
// Pipeline: detect -> convert(pack) -> kA(LN, bf16 out) -> kB(conv3x3 MFMA)
//   -> kC(eig MFMA + mean, bf16 out) -> kD(flux scan) -> kE(scan, bf16 u_out)
//   -> kF1(dec MFMA + LN) -> kMLP(MFMA MLP, fast gelu, vector epilogue)
// kMLP v2: phase-split GEMM1 (acc 32 regs not 64) + h1 stored in MFMA-frag
//   layout (16KB half-K LDS) -> LDS 25.6KB (5 blocks/CU vs 3), conflict-free
//   GEMM2 LDS reads, unrolled GEMM2 with register room to pipeline w2p loads.
// Workspace 192.7 MiB.

typedef __hip_bfloat16 bf16;
typedef __attribute__((ext_vector_type(8))) short bhalf8;   // 8 bf16 (4 VGPR)
typedef __attribute__((ext_vector_type(4))) float floatx4;  // MFMA C/D

#define DEV __device__ __forceinline__

DEV float b2f(const bf16 x) { return __bfloat162float(x); }
DEV bf16  f2b(float x)      { return __float2bfloat16(x); }
DEV unsigned short f2bu(float x) { bf16 h = f2b(x); return *(unsigned short*)&h; }
DEV float bu2f(unsigned short u) { unsigned int t = ((unsigned int)u) << 16; return *(float*)&t; }
DEV float softplusf(float x){ return x > 20.f ? x : log1pf(expf(x)); }
// gelu(x) = x * sigmoid(x*(a + b x^2)), a=2*0.7978845608, b=a*0.044715.
// log2(e) folded into constants so we hit v_exp_f32 (2^x) directly.
DEV float geluf(float x) {
    float v = x * fmaf(x * x, 0.10294324f, 2.30220819f);
    float e = __builtin_amdgcn_exp2f(-v);
    return x * __builtin_amdgcn_rcpf(1.f + e);
}

static constexpr int B_ = 2, T_ = 16, D_ = 64, HW = 4096;
static constexpr int NPIX = B_ * T_ * HW;               // 131072
static constexpr long long N1 = (long long)NPIX * 128;  // 16777216

// workspace offsets (floats). Total 50,505,792 floats = 192.7 MiB.
static constexpr long long BUFA  = 0;                   // x_eig bf16 (N1 ushort)
static constexpr long long XUBF  = N1;                  // xupd bf16 (N1 ushort)
static constexpr long long DECBF = N1 + N1 / 2;         // decoded bf16
static constexpr long long XNBF  = 2 * N1;              // xn bf16 -> dn bf16
static constexpr long long XCBF  = 2 * N1 + N1 / 2;     // xc bf16 -> u_out bf16
static constexpr long long XMEAN = 3 * N1;              // 4096 f32
static constexpr long long TABS  = XMEAN + 4096;        // 7 * 2048 f32
static constexpr long long FLAGO = TABS + 14336;        // 64
static constexpr long long WCP   = FLAGO + 64;          // conv w packed: 147456 ushort
static constexpr long long W1P   = WCP + 73728;         // 65536 ushort
static constexpr long long W2P   = W1P + 32768;         // 65536 ushort
static constexpr long long WEP   = W2P + 32768;         // 16384 ushort
static constexpr long long WDP   = WEP + 8192;          // 16384 ushort

// out offsets (elements)
static constexpr long long ZOUT = 0;
static constexpr long long HOUT = 16777216;
static constexpr long long FOUT = 17825792;

DEV float ld(const void* p, long long i, bool bf) {
    if (bf) return b2f(((const bf16*)p)[i]);
    return ((const float*)p)[i];
}

// ---- dtype detection --------------------------------------------------------
__global__ void k_detect(const unsigned short* __restrict__ x, float* __restrict__ ws) {
    int lane = threadIdx.x;
    int cnt = 0;
    for (int i = lane; i < 256; i += 64) {
        int e = (x[i] >> 7) & 0xFF;
        cnt += (e >= 100 && e <= 140) ? 1 : 0;
    }
    for (int m = 1; m < 64; m <<= 1) cnt += __shfl_xor(cnt, m, 64);
    if (lane == 0) ws[FLAGO] = (cnt >= 224) ? 1.f : 0.f;
}

// ---- weight pre-pack into MFMA B-fragment order -----------------------------
// B-frag: lane holds B[k = (lane>>4)*8 + j][n = lane&15], j=0..7 contiguous.
__global__ void k_convert(const void* Wc, const void* W1, const void* W2,
                          const void* Er, const void* Ei, const void* Dr, const void* Di,
                          float* ws) {
    bool bf = ws[FLAGO] != 0.f;
    int i = blockIdx.x * 256 + threadIdx.x;
    unsigned short* wcp = (unsigned short*)(ws + WCP);
    unsigned short* w1p = (unsigned short*)(ws + W1P);
    unsigned short* w2p = (unsigned short*)(ws + W2P);
    unsigned short* wep = (unsigned short*)(ws + WEP);
    unsigned short* wdp = (unsigned short*)(ws + WDP);
    if (i < 147456) {   // conv: [tap][kc(4)][nt(8)][lane][j]
        int j = i & 7, lane = (i >> 3) & 63, nt = (i >> 9) & 7, kc = (i >> 12) & 3, tap = i >> 14;
        int ic = kc * 32 + ((lane >> 4) << 3) + j, oc = nt * 16 + (lane & 15);
        wcp[i] = f2bu(ld(Wc, tap * 16384 + ic * 128 + oc, bf)); return;
    } i -= 147456;
    if (i < 65536) {    // W1 (128x512): [kc(4)][nt(32)][lane][j]
        int j = i & 7, lane = (i >> 3) & 63, nt = (i >> 9) & 31, kc = i >> 14;
        int ic = kc * 32 + ((lane >> 4) << 3) + j, oc = nt * 16 + (lane & 15);
        w1p[i] = f2bu(ld(W1, ic * 512 + oc, bf)); return;
    } i -= 65536;
    if (i < 65536) {    // W2 (512x128): [kc(16)][nt(8)][lane][j]
        int j = i & 7, lane = (i >> 3) & 63, nt = (i >> 9) & 7, kc = i >> 12;
        int ic = kc * 32 + ((lane >> 4) << 3) + j, oc = nt * 16 + (lane & 15);
        w2p[i] = f2bu(ld(W2, ic * 128 + oc, bf)); return;
    } i -= 65536;
    if (i < 16384) {    // WE = [[Er,Ei],[-Ei,Er]] (128x128): [kc(4)][nt(8)][lane][j]
        int j = i & 7, lane = (i >> 3) & 63, nt = (i >> 9) & 7, kc = i >> 12;
        int k = kc * 32 + ((lane >> 4) << 3) + j, n = nt * 16 + (lane & 15);
        float v;
        if (k < 64) v = (n < 64) ? ld(Er, k * 64 + n, bf) : ld(Ei, k * 64 + (n - 64), bf);
        else        v = (n < 64) ? -ld(Ei, (k - 64) * 64 + n, bf) : ld(Er, (k - 64) * 64 + (n - 64), bf);
        wep[i] = f2bu(v); return;
    } i -= 16384;
    if (i < 16384) {    // WD from Dec
        int j = i & 7, lane = (i >> 3) & 63, nt = (i >> 9) & 7, kc = i >> 12;
        int k = kc * 32 + ((lane >> 4) << 3) + j, n = nt * 16 + (lane & 15);
        float v;
        if (k < 64) v = (n < 64) ? ld(Dr, k * 64 + n, bf) : ld(Di, k * 64 + (n - 64), bf);
        else        v = (n < 64) ? -ld(Di, (k - 64) * 64 + n, bf) : ld(Dr, (k - 64) * 64 + (n - 64), bf);
        wdp[i] = f2bu(v); return;
    }
}

// ---- stage A: moveaxis + LN -> xc_bf, xn_bf (bf16) --------------------------
__global__ __launch_bounds__(256) void kA_ln(const void* __restrict__ xre,
                                             const void* __restrict__ xim,
                                             const void* __restrict__ gs,
                                             const void* __restrict__ bs,
                                             float* __restrict__ ws) {
    __shared__ unsigned short sr[64][72] __attribute__((aligned(16)));
    __shared__ unsigned short si[64][72] __attribute__((aligned(16)));
    __shared__ float red[2][4][64];
    __shared__ float mv[64], rv[64], gb[256];
    bool bf = ws[FLAGO] != 0.f;
    int blk = blockIdx.x;
    int bt = blk >> 6;                 // 0..31
    int px0 = (blk & 63) * 64;         // pixel group within image
    int tid = threadIdx.x;
    gb[tid] = (tid < 128) ? ld(gs, tid, bf) : ld(bs, tid - 128, bf);
    if (bf) {
        const unsigned short* xr16 = (const unsigned short*)xre;
        const unsigned short* xi16 = (const unsigned short*)xim;
        for (int l = tid; l < 1024; l += 256) {     // 2 arrays x 64 d x 8 chunks
            int a = l >> 9, dd = (l >> 3) & 63, ck = l & 7;
            long long src = (long long)bt * 262144 + (long long)dd * 4096 + px0 + ck * 8;
            bhalf8 v = *(const bhalf8*)&(a ? xi16 : xr16)[src];
            *(bhalf8*)&(a ? si : sr)[dd][ck * 8] = v;
        }
    } else {
        for (int l = tid; l < 8192; l += 256) {     // 2 arrays x 64 d x 64 px
            int a = l >> 12, dd = (l >> 6) & 63, px = l & 63;
            float v = ((const float*)(a ? xim : xre))[(long long)bt * 262144 + (long long)dd * 4096 + px0 + px];
            (a ? si : sr)[dd][px] = f2bu(v);
        }
    }
    __syncthreads();
    int px = tid & 63, part = tid >> 6;
    float s = 0.f, ss = 0.f;
    for (int d = part * 16; d < part * 16 + 16; d++) {
        float r = bu2f(sr[d][px]), q = bu2f(si[d][px]);
        s += r + q; ss += r * r + q * q;
    }
    red[0][part][px] = s; red[1][part][px] = ss;
    __syncthreads();
    if (tid < 64) {
        float S  = red[0][0][tid] + red[0][1][tid] + red[0][2][tid] + red[0][3][tid];
        float SS = red[1][0][tid] + red[1][1][tid] + red[1][2][tid] + red[1][3][tid];
        float m = S * (1.f / 128.f);
        mv[tid] = m;
        rv[tid] = rsqrtf(SS * (1.f / 128.f) - m * m + 1e-5f);
    }
    __syncthreads();
    unsigned short* xcb = (unsigned short*)(ws + XCBF);
    unsigned short* xnb = (unsigned short*)(ws + XNBF);
    long long pbase = ((long long)bt * 4096 + px0) * 128;
    for (int l = tid; l < 8192; l += 256) {
        int p2 = l >> 7, ch = l & 127, d = ch & 63;
        unsigned short raw = (ch < 64 ? sr : si)[d][p2];
        float v = bu2f(raw);
        xcb[pbase + p2 * 128 + ch] = raw;
        xnb[pbase + p2 * 128 + ch] = f2bu((v - mv[p2]) * rv[p2] * gb[ch] + gb[128 + ch]);
    }
}

// ---- stage B: 3x3 conv 128->128 MFMA implicit GEMM, + x + bc -> xupd bf16 ---
__global__ __launch_bounds__(256) void kB_conv(const void* __restrict__ bc,
                                               float* __restrict__ ws) {
    __shared__ unsigned short xt[3][64][136] __attribute__((aligned(16)));
    bool bf = ws[FLAGO] != 0.f;
    int blk = blockIdx.x, bt = blk >> 6, h = blk & 63;
    int tid = threadIdx.x, lane = tid & 63, wv = tid >> 6;
    int m16 = lane & 15, quad = lane >> 4;
    const unsigned short* xnb = (const unsigned short*)(ws + XNBF);
    const unsigned short* wcp = (const unsigned short*)(ws + WCP);
    bhalf8 zero8 = {0, 0, 0, 0, 0, 0, 0, 0};
    for (int l = tid; l < 3072; l += 256) {   // 3 rows x 64 cols x 16 chunks
        int r = l >> 10, rem = l & 1023, col = rem >> 4, ck = rem & 15;
        int hr = h - 1 + r;
        bhalf8 v = zero8;
        if (hr >= 0 && hr < 64)
            v = *(const bhalf8*)&xnb[(((long long)bt * 4096 + hr * 64 + col) << 7) + ck * 8];
        *(bhalf8*)&xt[r][col][ck * 8] = v;
    }
    __syncthreads();
    floatx4 acc[4][2];
    #pragma unroll
    for (int mt = 0; mt < 4; mt++)
        #pragma unroll
        for (int nt = 0; nt < 2; nt++)
            acc[mt][nt] = (floatx4){0.f, 0.f, 0.f, 0.f};
    for (int tap = 0; tap < 9; tap++) {
        int dy = tap / 3, dx = tap - dy * 3;
        #pragma unroll
        for (int kc = 0; kc < 4; kc++) {
            bhalf8 bfr[2];
            #pragma unroll
            for (int nt = 0; nt < 2; nt++)
                bfr[nt] = *(const bhalf8*)&wcp[((((tap * 4 + kc) * 8) + (wv * 2 + nt)) * 64 + lane) * 8];
            #pragma unroll
            for (int mt = 0; mt < 4; mt++) {
                int col = mt * 16 + m16 + dx - 1;
                bhalf8 af = zero8;
                if (col >= 0 && col < 64)
                    af = *(const bhalf8*)&xt[dy][col][kc * 32 + quad * 8];
                acc[mt][0] = __builtin_amdgcn_mfma_f32_16x16x32_bf16(af, bfr[0], acc[mt][0], 0, 0, 0);
                acc[mt][1] = __builtin_amdgcn_mfma_f32_16x16x32_bf16(af, bfr[1], acc[mt][1], 0, 0, 0);
            }
        }
    }
    const unsigned short* xcb = (const unsigned short*)(ws + XCBF);
    unsigned short* xub = (unsigned short*)(ws + XUBF);
    #pragma unroll
    for (int nt = 0; nt < 2; nt++) {
        int n = wv * 32 + nt * 16 + m16;
        float bcv = ld(bc, n, bf);
        #pragma unroll
        for (int mt = 0; mt < 4; mt++)
            #pragma unroll
            for (int r = 0; r < 4; r++) {
                int m = mt * 16 + quad * 4 + r;
                long long p = (long long)bt * 4096 + h * 64 + m;
                xub[p * 128 + n] = f2bu(acc[mt][nt][r] + bu2f(xcb[p * 128 + n]) + bcv);
            }
    }
}

// ---- stage C: x_eig = xupd @ WE (MFMA) -> BUFA bf16, + x_mean atomics -------
__global__ __launch_bounds__(256) void kC_eig(float* __restrict__ ws) {
    __shared__ unsigned short At[64][136] __attribute__((aligned(16)));
    int blk = blockIdx.x, bt = blk >> 6;
    long long px0 = (long long)blk * 64;
    int tid = threadIdx.x, lane = tid & 63, wv = tid >> 6;
    int m16 = lane & 15, quad = lane >> 4;
    const unsigned short* xub = (const unsigned short*)(ws + XUBF);
    for (int l = tid; l < 1024; l += 256) {   // 64 px x 16 chunks
        int p2 = l >> 4, ck = l & 15;
        *(bhalf8*)&At[p2][ck * 8] = *(const bhalf8*)&xub[(px0 + p2) * 128 + ck * 8];
    }
    __syncthreads();
    const unsigned short* wep = (const unsigned short*)(ws + WEP);
    floatx4 acc[4][2];
    #pragma unroll
    for (int mt = 0; mt < 4; mt++)
        #pragma unroll
        for (int nt = 0; nt < 2; nt++)
            acc[mt][nt] = (floatx4){0.f, 0.f, 0.f, 0.f};
    #pragma unroll
    for (int kc = 0; kc < 4; kc++) {
        bhalf8 bfr[2];
        #pragma unroll
        for (int nt = 0; nt < 2; nt++)
            bfr[nt] = *(const bhalf8*)&wep[(((kc * 8) + wv * 2 + nt) * 64 + lane) * 8];
        #pragma unroll
        for (int mt = 0; mt < 4; mt++) {
            bhalf8 af = *(const bhalf8*)&At[mt * 16 + m16][kc * 32 + quad * 8];
            acc[mt][0] = __builtin_amdgcn_mfma_f32_16x16x32_bf16(af, bfr[0], acc[mt][0], 0, 0, 0);
            acc[mt][1] = __builtin_amdgcn_mfma_f32_16x16x32_bf16(af, bfr[1], acc[mt][1], 0, 0, 0);
        }
    }
    unsigned short* xeb = (unsigned short*)(ws + BUFA);
    #pragma unroll
    for (int nt = 0; nt < 2; nt++) {
        int n = wv * 32 + nt * 16 + m16;
        float part = 0.f;
        #pragma unroll
        for (int mt = 0; mt < 4; mt++)
            #pragma unroll
            for (int r = 0; r < 4; r++) {
                int m = mt * 16 + quad * 4 + r;
                xeb[(px0 + m) * 128 + n] = f2bu(acc[mt][nt][r]);
                part += acc[mt][nt][r];
            }
        part += __shfl_xor(part, 16, 64);
        part += __shfl_xor(part, 32, 64);
        if (quad == 0) atomicAdd(ws + XMEAN + bt * 128 + n, part);
    }
}

// ---- stage D: flux recurrence, source, gate, op tables, flux_out ------------
__global__ __launch_bounds__(256) void kD_flux(const void* __restrict__ fxr, const void* __restrict__ fxi,
                                               const void* __restrict__ dtseq, const void* __restrict__ lamflux,
                                               const void* __restrict__ Wsr, const void* __restrict__ Wsi,
                                               const void* __restrict__ wgate, const void* __restrict__ bgate,
                                               const void* __restrict__ lamreraw, const void* __restrict__ lamim,
                                               float* __restrict__ ws, void* __restrict__ outv) {
    bool bfo = ws[FLAGO] != 0.f;
    int b = blockIdx.x;
    int tid = threadIdx.x;
    int d = tid & 63, g = tid >> 6;
    __shared__ float fr[64], fi[64], psr[4][64], psi[4][64];
    float lam_f = softplusf(ld(lamflux, d, bfo));
    float lre = -softplusf(ld(lamreraw, d, bfo));
    float lim = ld(lamim, d, bfo);
    float cr = 0.f, ci = 0.f;
    if (g == 0) { cr = ld(fxr, b * 64 + d, bfo); ci = ld(fxi, b * 64 + d, bfo); }
    float* tabs = ws + TABS;
    const float* xmean = ws + XMEAN;
    for (int t = 0; t < 16; t++) {
        float dt = ld(dtseq, b * 16 + t, bfo);
        int idx = b * 1024 + t * 64 + d;
        if (g == 0) {
            float A = expf(-lam_f * dt);
            float xr = xmean[(b * 16 + t) * 128 + d]      * (1.f / 4096.f) * dt;
            float xq = xmean[(b * 16 + t) * 128 + 64 + d] * (1.f / 4096.f) * dt;
            cr = A * cr + xr; ci = A * ci + xq;
            fr[d] = cr; fi[d] = ci;
        }
        __syncthreads();
        {
            float pr = 0.f, pi = 0.f;
            #pragma unroll
            for (int k = 0; k < 16; k++) {
                int d2 = g * 16 + k;
                float wr = ld(Wsr, d2 * 64 + d, bfo), wi = ld(Wsi, d2 * 64 + d, bfo);
                pr += fr[d2] * wr - fi[d2] * wi;
                pi += fr[d2] * wi + fi[d2] * wr;
            }
            psr[g][d] = pr; psi[g][d] = pi;
        }
        if (g == 1) {
            float od  = expf(lre * dt);
            float odr = od * cosf(lim * dt);
            float odi = od * sinf(lim * dt);
            tabs[3 * 2048 + idx] = odr; tabs[4 * 2048 + idx] = odi;
            float den = lre * lre + lim * lim;
            float tr = odr - 1.f;
            tabs[5 * 2048 + idx] = (tr * lre + odi * lim) / den;
            tabs[6 * 2048 + idx] = (odi * lre - tr * lim) / den;
        }
        __syncthreads();
        if (g == 0) {
            float sr = psr[0][d] + psr[1][d] + psr[2][d] + psr[3][d];
            float si2 = psi[0][d] + psi[1][d] + psi[2][d] + psi[3][d];
            tabs[1 * 2048 + idx] = sr; tabs[2 * 2048 + idx] = si2;
            tabs[0 * 2048 + idx] = 1.f / (1.f + expf(-(cr * ld(wgate, d, bfo) + ld(bgate, d, bfo))));
            if (t == 15) {
                if (bfo) {
                    bf16* ob = (bf16*)outv;
                    ob[FOUT + (b * 64 + d) * 2]     = f2b(cr);
                    ob[FOUT + (b * 64 + d) * 2 + 1] = f2b(ci);
                } else {
                    float* of = (float*)outv;
                    of[FOUT + (b * 64 + d) * 2]     = cr;
                    of[FOUT + (b * 64 + d) * 2 + 1] = ci;
                }
            }
        }
    }
}

// ---- stage E: time recurrence; x_eig bf16 in BUFA -> u_out bf16 in XCBF -----
__global__ __launch_bounds__(256) void kE_scan(const void* __restrict__ hre,
                                               const void* __restrict__ him,
                                               float* __restrict__ ws, void* __restrict__ outv) {
    __shared__ float tab[7][16][64];
    bool bfo = ws[FLAGO] != 0.f;
    long long G = (long long)blockIdx.x * 256 + threadIdx.x;
    int d = threadIdx.x & 63;
    int pix = (int)((G >> 6) & 4095);
    int b = (int)(G >> 18);
    const float* tabs = ws + TABS;
    for (int l = threadIdx.x; l < 7 * 1024; l += 256) {
        int a = l >> 10, idx = l & 1023;
        ((float*)tab)[l] = tabs[a * 2048 + b * 1024 + idx];
    }
    __syncthreads();
    long long hidx = ((long long)b * 4096 + pix) * 64 + d;
    float cr = ld(hre, hidx, bfo), ci = ld(him, hidx, bfo);
    const unsigned short* xe = (const unsigned short*)(ws + BUFA);
    unsigned short* ub = (unsigned short*)(ws + XCBF);
    for (int t = 0; t < 16; t++) {
        long long base = ((long long)((b * 16 + t) * 4096 + pix)) * 128 + d;
        float xr = bu2f(xe[base]), xi = bu2f(xe[base + 64]);
        float gt = tab[0][t][d], sr = tab[1][t][d], si = tab[2][t][d];
        float odr = tab[3][t][d], odi = tab[4][t][d];
        float ofr = tab[5][t][d], ofi = tab[6][t][d];
        float fre = xr * gt + sr * (1.f - gt);
        float fim = xi * gt + si * (1.f - gt);
        float ure = fre * ofr - fim * ofi;
        float uim = fre * ofi + fim * ofr;
        float ncr = odr * cr - odi * ci + ure;
        float nci = odr * ci + odi * cr + uim;
        cr = ncr; ci = nci;
        ub[base] = f2bu(cr); ub[base + 64] = f2bu(ci);
    }
    if (bfo) {
        __hip_bfloat162 hv; hv.x = f2b(cr); hv.y = f2b(ci);
        ((__hip_bfloat162*)((bf16*)outv + HOUT))[hidx] = hv;
    } else {
        float2 hv; hv.x = cr; hv.y = ci;
        ((float2*)((float*)outv + HOUT))[hidx] = hv;
    }
}

// ---- stage F1: decoded = u_out(bf16) @ WD (MFMA) -> DECBF bf16, LN -> dn ----
__global__ __launch_bounds__(256) void kF1_dec(const void* __restrict__ gt_,
                                               const void* __restrict__ bt_,
                                               float* __restrict__ ws) {
    __shared__ unsigned short At[64][136] __attribute__((aligned(16)));
    __shared__ float Ct[64][132];
    __shared__ float mv[64], rv[64], gbt[256];
    bool bf = ws[FLAGO] != 0.f;
    long long px0 = (long long)blockIdx.x * 64;
    int tid = threadIdx.x, lane = tid & 63, wv = tid >> 6;
    int m16 = lane & 15, quad = lane >> 4;
    gbt[tid] = (tid < 128) ? ld(gt_, tid, bf) : ld(bt_, tid - 128, bf);
    const unsigned short* uo = (const unsigned short*)(ws + XCBF);
    for (int l = tid; l < 1024; l += 256) {
        int p2 = l >> 4, ck = l & 15;
        *(bhalf8*)&At[p2][ck * 8] = *(const bhalf8*)&uo[(px0 + p2) * 128 + ck * 8];
    }
    __syncthreads();
    const unsigned short* wdp = (const unsigned short*)(ws + WDP);
    floatx4 acc[4][2];
    #pragma unroll
    for (int mt = 0; mt < 4; mt++)
        #pragma unroll
        for (int nt = 0; nt < 2; nt++)
            acc[mt][nt] = (floatx4){0.f, 0.f, 0.f, 0.f};
    #pragma unroll
    for (int kc = 0; kc < 4; kc++) {
        bhalf8 bfr[2];
        #pragma unroll
        for (int nt = 0; nt < 2; nt++)
            bfr[nt] = *(const bhalf8*)&wdp[(((kc * 8) + wv * 2 + nt) * 64 + lane) * 8];
        #pragma unroll
        for (int mt = 0; mt < 4; mt++) {
            bhalf8 af = *(const bhalf8*)&At[mt * 16 + m16][kc * 32 + quad * 8];
            acc[mt][0] = __builtin_amdgcn_mfma_f32_16x16x32_bf16(af, bfr[0], acc[mt][0], 0, 0, 0);
            acc[mt][1] = __builtin_amdgcn_mfma_f32_16x16x32_bf16(af, bfr[1], acc[mt][1], 0, 0, 0);
        }
    }
    #pragma unroll
    for (int nt = 0; nt < 2; nt++) {
        int n = wv * 32 + nt * 16 + m16;
        #pragma unroll
        for (int mt = 0; mt < 4; mt++)
            #pragma unroll
            for (int r = 0; r < 4; r++)
                Ct[mt * 16 + quad * 4 + r][n] = acc[mt][nt][r];
    }
    __syncthreads();
    if (tid < 64) {
        float s = 0.f, ss = 0.f;
        for (int ch = 0; ch < 128; ch++) { float v = Ct[tid][ch]; s += v; ss += v * v; }
        float m = s * (1.f / 128.f);
        mv[tid] = m;
        rv[tid] = rsqrtf(ss * (1.f / 128.f) - m * m + 1e-5f);
    }
    __syncthreads();
    unsigned short* decb = (unsigned short*)(ws + DECBF);
    unsigned short* dnb  = (unsigned short*)(ws + XNBF);   // xn is dead
    for (int l = tid; l < 8192; l += 256) {
        int p2 = l >> 7, ch = l & 127;
        float v = Ct[p2][ch];
        decb[(px0 + p2) * 128 + ch] = f2bu(v);
        dnb [(px0 + p2) * 128 + ch] = f2bu((v - mv[p2]) * rv[p2] * gbt[ch] + gbt[128 + ch]);
    }
}

// ---- stage F2+F3 fused: MFMA MLP (128->512 gelu ->128) + vector z write -----
// v2: two-phase GEMM1 (4 n-tiles at a time, 32-reg acc) -> gelu -> scatter
// into MFMA-A-fragment-layout LDS h1f[slot][mt][lane][8] (16KB, half-K) ->
// partial GEMM2 accumulation. LDS 25.6KB total; GEMM2 A-reads are lane-major
// ds_read_b128 (conflict-free); 5 blocks/CU requested.
__global__ __launch_bounds__(256, 5) void kMLP(const void* __restrict__ b1v,
                                               const void* __restrict__ b2v,
                                               float* __restrict__ ws, void* __restrict__ outv) {
    __shared__ unsigned short A1[32][136] __attribute__((aligned(16)));
    __shared__ unsigned short h1f[8][2][64][8] __attribute__((aligned(16)));  // 16 KB
    __shared__ float gb2[128];
    bool bf = ws[FLAGO] != 0.f;
    long long px0 = (long long)blockIdx.x * 32;
    int tid = threadIdx.x, lane = tid & 63, wv = tid >> 6;
    int m16 = lane & 15, quad = lane >> 4;
    const unsigned short* dnb = (const unsigned short*)(ws + XNBF);
    if (tid < 128) gb2[tid] = ld(b2v, tid, bf);
    for (int l = tid; l < 512; l += 256) {
        int p2 = l >> 4, ck = l & 15;
        *(bhalf8*)&A1[p2][ck * 8] = *(const bhalf8*)&dnb[(px0 + p2) * 128 + ck * 8];
    }
    __syncthreads();
    const unsigned short* w1p = (const unsigned short*)(ws + W1P);
    const unsigned short* w2p = (const unsigned short*)(ws + W2P);
    floatx4 acc2[2][2];
    #pragma unroll
    for (int mt = 0; mt < 2; mt++)
        #pragma unroll
        for (int nt = 0; nt < 2; nt++)
            acc2[mt][nt] = (floatx4){0.f, 0.f, 0.f, 0.f};

    #pragma unroll
    for (int ph = 0; ph < 2; ph++) {
        // ---- GEMM1 half: n-tiles (wv*8 + ph*4 + 0..3), acc = 32 regs ----
        floatx4 acc1[2][4];
        #pragma unroll
        for (int mt = 0; mt < 2; mt++)
            #pragma unroll
            for (int nt4 = 0; nt4 < 4; nt4++)
                acc1[mt][nt4] = (floatx4){0.f, 0.f, 0.f, 0.f};
        #pragma unroll
        for (int kc = 0; kc < 4; kc++) {
            bhalf8 af0 = *(const bhalf8*)&A1[m16][kc * 32 + quad * 8];
            bhalf8 af1 = *(const bhalf8*)&A1[16 + m16][kc * 32 + quad * 8];
            #pragma unroll
            for (int nt4 = 0; nt4 < 4; nt4++) {
                int nt = ph * 4 + nt4;
                bhalf8 bfr = *(const bhalf8*)&w1p[(((kc * 32) + wv * 8 + nt) * 64 + lane) * 8];
                acc1[0][nt4] = __builtin_amdgcn_mfma_f32_16x16x32_bf16(af0, bfr, acc1[0][nt4], 0, 0, 0);
                acc1[1][nt4] = __builtin_amdgcn_mfma_f32_16x16x32_bf16(af1, bfr, acc1[1][nt4], 0, 0, 0);
            }
        }
        // ---- bias + gelu + scatter into A-fragment layout ----
        // value h1[m = mt*16+quad*4+r][n = (wv*8+nt)*16+m16] goes to
        // h1f[slot = wv*2+(nt4>>1)][mt][lane' = qp*16 + quad*4 + r][j = m16&7]
        // with qp = (2*nt + (m16>>3)) & 3; k-block kc2g = 4*wv + (nt4>>1) + 2*ph.
        #pragma unroll
        for (int nt4 = 0; nt4 < 4; nt4++) {
            int nt = ph * 4 + nt4;
            int n = (wv * 8 + nt) * 16 + m16;
            float b1f = ld(b1v, n, bf);
            int qp = ((nt * 2) + (m16 >> 3)) & 3;
            int slot = wv * 2 + (nt4 >> 1);
            int j = m16 & 7;
            #pragma unroll
            for (int mt = 0; mt < 2; mt++)
                #pragma unroll
                for (int r = 0; r < 4; r++)
                    h1f[slot][mt][qp * 16 + quad * 4 + r][j] =
                        f2bu(geluf(acc1[mt][nt4][r] + b1f));
        }
        __syncthreads();
        // ---- GEMM2 partial: 8 k-blocks of this phase ----
        #pragma unroll
        for (int s = 0; s < 8; s++) {
            int kc2g = (s >> 1) * 4 + (s & 1) + ph * 2;   // k-block index in w2p
            bhalf8 a0 = *(const bhalf8*)&h1f[s][0][lane][0];
            bhalf8 a1 = *(const bhalf8*)&h1f[s][1][lane][0];
            #pragma unroll
            for (int nt = 0; nt < 2; nt++) {
                bhalf8 bfr = *(const bhalf8*)&w2p[(((kc2g * 8) + wv * 2 + nt) * 64 + lane) * 8];
                acc2[0][nt] = __builtin_amdgcn_mfma_f32_16x16x32_bf16(a0, bfr, acc2[0][nt], 0, 0, 0);
                acc2[1][nt] = __builtin_amdgcn_mfma_f32_16x16x32_bf16(a1, bfr, acc2[1][nt], 0, 0, 0);
            }
        }
        if (ph == 0) __syncthreads();   // h1f consumed before phase-1 overwrite
    }
    // ---- round-trip C through LDS (reuse A1) for pixel-major epilogue ----
    // A1 reads all completed (barrier after phase-1 scatter); h1f reads by
    // other waves don't touch A1, so no extra barrier needed before writes.
    #pragma unroll
    for (int nt = 0; nt < 2; nt++) {
        int n = wv * 32 + nt * 16 + m16;
        #pragma unroll
        for (int mt = 0; mt < 2; mt++)
            #pragma unroll
            for (int r = 0; r < 4; r++)
                A1[mt * 16 + quad * 4 + r][n] = f2bu(acc2[mt][nt][r]);
    }
    __syncthreads();
    {
        const unsigned short* decb = (const unsigned short*)(ws + DECBF);
        const unsigned short* xub  = (const unsigned short*)(ws + XUBF);
        int pxl = tid >> 3, dc = (tid & 7) * 8;
        long long p = px0 + pxl;
        bhalf8 cre = *(const bhalf8*)&A1[pxl][dc];
        bhalf8 cim = *(const bhalf8*)&A1[pxl][64 + dc];
        bhalf8 xr8 = *(const bhalf8*)&xub[p * 128 + dc];
        bhalf8 xi8 = *(const bhalf8*)&xub[p * 128 + 64 + dc];
        bhalf8 dr8 = *(const bhalf8*)&decb[p * 128 + dc];
        bhalf8 di8 = *(const bhalf8*)&decb[p * 128 + 64 + dc];
        float zr[8], zi[8];
        #pragma unroll
        for (int k = 0; k < 8; k++) {
            zr[k] = bu2f((unsigned short)cre[k]) + gb2[dc + k]
                  + bu2f((unsigned short)xr8[k]) + bu2f((unsigned short)dr8[k]);
            zi[k] = bu2f((unsigned short)cim[k]) + gb2[64 + dc + k]
                  + bu2f((unsigned short)xi8[k]) + bu2f((unsigned short)di8[k]);
        }
        if (bf) {
            unsigned short o[16];
            #pragma unroll
            for (int k = 0; k < 8; k++) { o[2 * k] = f2bu(zr[k]); o[2 * k + 1] = f2bu(zi[k]); }
            unsigned short* ob = (unsigned short*)outv;
            *(bhalf8*)&ob[ZOUT + p * 128 + 2 * dc]     = *(bhalf8*)&o[0];
            *(bhalf8*)&ob[ZOUT + p * 128 + 2 * dc + 8] = *(bhalf8*)&o[8];
        } else {
            float* of = (float*)outv + ZOUT + p * 128 + 2 * dc;
            #pragma unroll
            for (int k = 0; k < 8; k++) { of[2 * k] = zr[k]; of[2 * k + 1] = zi[k]; }
        }
    }
}

extern "C" void kernel_launch(void* const* d_in, const int* in_sizes, int n_in,
                              void* d_out, int out_size, void* d_ws, size_t ws_size,
                              hipStream_t stream) {
    const void* x_re  = d_in[0];
    const void* x_im  = d_in[1];
    const void* h_re  = d_in[2];
    const void* h_im  = d_in[3];
    const void* fl_re = d_in[4];
    const void* fl_im = d_in[5];
    const void* dtseq = d_in[6];
    const void* g_s   = d_in[7];
    const void* b_s   = d_in[8];
    const void* Wc    = d_in[9];
    const void* bc    = d_in[10];
    const void* g_t   = d_in[11];
    const void* b_t   = d_in[12];
    const void* E_re  = d_in[13];
    const void* E_im  = d_in[14];
    const void* De_re = d_in[15];
    const void* De_im = d_in[16];
    const void* lamfl = d_in[17];
    const void* Ws_re = d_in[18];
    const void* Ws_im = d_in[19];
    const void* wgate = d_in[20];
    const void* bgate = d_in[21];
    const void* lamrr = d_in[22];
    const void* lamim = d_in[23];
    const void* W1    = d_in[24];
    const void* b1    = d_in[25];
    const void* W2    = d_in[26];
    const void* b2    = d_in[27];
    float* ws = (float*)d_ws;

    hipMemsetAsync((char*)d_ws + XMEAN * sizeof(float), 0, 4096 * sizeof(float), stream);
    k_detect<<<1, 64, 0, stream>>>((const unsigned short*)x_re, ws);
    k_convert<<<1216, 256, 0, stream>>>(Wc, W1, W2, E_re, E_im, De_re, De_im, ws);
    kA_ln<<<2048, 256, 0, stream>>>(x_re, x_im, g_s, b_s, ws);
    kB_conv<<<2048, 256, 0, stream>>>(bc, ws);
    kC_eig<<<2048, 256, 0, stream>>>(ws);
    kD_flux<<<2, 256, 0, stream>>>(fl_re, fl_im, dtseq, lamfl, Ws_re, Ws_im,
                                   wgate, bgate, lamrr, lamim, ws, d_out);
    kE_scan<<<2048, 256, 0, stream>>>(h_re, h_im, ws, d_out);
    kF1_dec<<<2048, 256, 0, stream>>>(g_t, b_t, ws);
    kMLP<<<4096, 256, 0, stream>>>(b1, b2, ws, d_out);
}

// Round 2
// 414.912 us; speedup vs baseline: 1.0948x; 1.0853x over previous
//
#include <hip/hip_runtime.h>
#include <hip/hip_bf16.h>

// UniPhyBlock: B=2,T=16,D=64,H=64,W=64. Outputs bf16; internal f32 accum,
// bf16 MFMA for conv / eig / dec / MLP. Input dtype auto-detected.
// Pipeline v3 (fused): detect -> convert -> kA(LN) -> kB(conv3x3 MFMA + eig
//   MFMA + mean)  -> kD(flux) -> kE(scan, 2ch/thread) -> kMLP(dec MFMA + LN
//   + MLP MFMA + z epilogue).  kC and kF1 eliminated; decoded/dn never hit HBM.
// Workspace 192.7 MiB (layout unchanged; DECBF now unused).

typedef __hip_bfloat16 bf16;
typedef __attribute__((ext_vector_type(8))) short bhalf8;   // 8 bf16 (4 VGPR)
typedef __attribute__((ext_vector_type(4))) float floatx4;  // MFMA C/D

#define DEV __device__ __forceinline__

DEV float b2f(const bf16 x) { return __bfloat162float(x); }
DEV bf16  f2b(float x)      { return __float2bfloat16(x); }
DEV unsigned short f2bu(float x) { bf16 h = f2b(x); return *(unsigned short*)&h; }
DEV float bu2f(unsigned short u) { unsigned int t = ((unsigned int)u) << 16; return *(float*)&t; }
DEV float softplusf(float x){ return x > 20.f ? x : log1pf(expf(x)); }
// gelu(x) = x * sigmoid(x*(a + b x^2)); log2(e) folded so v_exp_f32 is direct.
DEV float geluf(float x) {
    float v = x * fmaf(x * x, 0.10294324f, 2.30220819f);
    float e = __builtin_amdgcn_exp2f(-v);
    return x * __builtin_amdgcn_rcpf(1.f + e);
}

static constexpr int B_ = 2, T_ = 16, D_ = 64, HW = 4096;
static constexpr int NPIX = B_ * T_ * HW;               // 131072
static constexpr long long N1 = (long long)NPIX * 128;  // 16777216

// workspace offsets (floats). Total 50,505,792 floats = 192.7 MiB.
static constexpr long long BUFA  = 0;                   // x_eig bf16 (N1 ushort)
static constexpr long long XUBF  = N1;                  // xupd bf16 (N1 ushort)
static constexpr long long DECBF = N1 + N1 / 2;         // (unused in v3)
static constexpr long long XNBF  = 2 * N1;              // xn bf16
static constexpr long long XCBF  = 2 * N1 + N1 / 2;     // xc bf16 -> u_out bf16
static constexpr long long XMEAN = 3 * N1;              // 4096 f32
static constexpr long long TABS  = XMEAN + 4096;        // 7 * 2048 f32
static constexpr long long FLAGO = TABS + 14336;        // 64
static constexpr long long WCP   = FLAGO + 64;          // conv w packed: 147456 ushort
static constexpr long long W1P   = WCP + 73728;         // 65536 ushort
static constexpr long long W2P   = W1P + 32768;         // 65536 ushort
static constexpr long long WEP   = W2P + 32768;         // 16384 ushort
static constexpr long long WDP   = WEP + 8192;          // 16384 ushort

// out offsets (elements)
static constexpr long long ZOUT = 0;
static constexpr long long HOUT = 16777216;
static constexpr long long FOUT = 17825792;

DEV float ld(const void* p, long long i, bool bf) {
    if (bf) return b2f(((const bf16*)p)[i]);
    return ((const float*)p)[i];
}

// ---- dtype detection --------------------------------------------------------
__global__ void k_detect(const unsigned short* __restrict__ x, float* __restrict__ ws) {
    int lane = threadIdx.x;
    int cnt = 0;
    for (int i = lane; i < 256; i += 64) {
        int e = (x[i] >> 7) & 0xFF;
        cnt += (e >= 100 && e <= 140) ? 1 : 0;
    }
    for (int m = 1; m < 64; m <<= 1) cnt += __shfl_xor(cnt, m, 64);
    if (lane == 0) ws[FLAGO] = (cnt >= 224) ? 1.f : 0.f;
}

// ---- weight pre-pack into MFMA B-fragment order -----------------------------
// B-frag: lane holds B[k = (lane>>4)*8 + j][n = lane&15], j=0..7 contiguous.
__global__ void k_convert(const void* Wc, const void* W1, const void* W2,
                          const void* Er, const void* Ei, const void* Dr, const void* Di,
                          float* ws) {
    bool bf = ws[FLAGO] != 0.f;
    int i = blockIdx.x * 256 + threadIdx.x;
    unsigned short* wcp = (unsigned short*)(ws + WCP);
    unsigned short* w1p = (unsigned short*)(ws + W1P);
    unsigned short* w2p = (unsigned short*)(ws + W2P);
    unsigned short* wep = (unsigned short*)(ws + WEP);
    unsigned short* wdp = (unsigned short*)(ws + WDP);
    if (i < 147456) {   // conv: [tap][kc(4)][nt(8)][lane][j]
        int j = i & 7, lane = (i >> 3) & 63, nt = (i >> 9) & 7, kc = (i >> 12) & 3, tap = i >> 14;
        int ic = kc * 32 + ((lane >> 4) << 3) + j, oc = nt * 16 + (lane & 15);
        wcp[i] = f2bu(ld(Wc, tap * 16384 + ic * 128 + oc, bf)); return;
    } i -= 147456;
    if (i < 65536) {    // W1 (128x512): [kc(4)][nt(32)][lane][j]
        int j = i & 7, lane = (i >> 3) & 63, nt = (i >> 9) & 31, kc = i >> 14;
        int ic = kc * 32 + ((lane >> 4) << 3) + j, oc = nt * 16 + (lane & 15);
        w1p[i] = f2bu(ld(W1, ic * 512 + oc, bf)); return;
    } i -= 65536;
    if (i < 65536) {    // W2 (512x128): [kc(16)][nt(8)][lane][j]
        int j = i & 7, lane = (i >> 3) & 63, nt = (i >> 9) & 7, kc = i >> 12;
        int ic = kc * 32 + ((lane >> 4) << 3) + j, oc = nt * 16 + (lane & 15);
        w2p[i] = f2bu(ld(W2, ic * 128 + oc, bf)); return;
    } i -= 65536;
    if (i < 16384) {    // WE = [[Er,Ei],[-Ei,Er]] (128x128): [kc(4)][nt(8)][lane][j]
        int j = i & 7, lane = (i >> 3) & 63, nt = (i >> 9) & 7, kc = i >> 12;
        int k = kc * 32 + ((lane >> 4) << 3) + j, n = nt * 16 + (lane & 15);
        float v;
        if (k < 64) v = (n < 64) ? ld(Er, k * 64 + n, bf) : ld(Ei, k * 64 + (n - 64), bf);
        else        v = (n < 64) ? -ld(Ei, (k - 64) * 64 + n, bf) : ld(Er, (k - 64) * 64 + (n - 64), bf);
        wep[i] = f2bu(v); return;
    } i -= 16384;
    if (i < 16384) {    // WD from Dec
        int j = i & 7, lane = (i >> 3) & 63, nt = (i >> 9) & 7, kc = i >> 12;
        int k = kc * 32 + ((lane >> 4) << 3) + j, n = nt * 16 + (lane & 15);
        float v;
        if (k < 64) v = (n < 64) ? ld(Dr, k * 64 + n, bf) : ld(Di, k * 64 + (n - 64), bf);
        else        v = (n < 64) ? -ld(Di, (k - 64) * 64 + n, bf) : ld(Dr, (k - 64) * 64 + (n - 64), bf);
        wdp[i] = f2bu(v); return;
    }
}

// ---- stage A: moveaxis + LN -> xc_bf, xn_bf (bf16) --------------------------
__global__ __launch_bounds__(256) void kA_ln(const void* __restrict__ xre,
                                             const void* __restrict__ xim,
                                             const void* __restrict__ gs,
                                             const void* __restrict__ bs,
                                             float* __restrict__ ws) {
    __shared__ unsigned short sr[64][72] __attribute__((aligned(16)));
    __shared__ unsigned short si[64][72] __attribute__((aligned(16)));
    __shared__ float red[2][4][64];
    __shared__ float mv[64], rv[64], gb[256];
    bool bf = ws[FLAGO] != 0.f;
    int blk = blockIdx.x;
    int bt = blk >> 6;                 // 0..31
    int px0 = (blk & 63) * 64;         // pixel group within image
    int tid = threadIdx.x;
    gb[tid] = (tid < 128) ? ld(gs, tid, bf) : ld(bs, tid - 128, bf);
    if (bf) {
        const unsigned short* xr16 = (const unsigned short*)xre;
        const unsigned short* xi16 = (const unsigned short*)xim;
        for (int l = tid; l < 1024; l += 256) {     // 2 arrays x 64 d x 8 chunks
            int a = l >> 9, dd = (l >> 3) & 63, ck = l & 7;
            long long src = (long long)bt * 262144 + (long long)dd * 4096 + px0 + ck * 8;
            bhalf8 v = *(const bhalf8*)&(a ? xi16 : xr16)[src];
            *(bhalf8*)&(a ? si : sr)[dd][ck * 8] = v;
        }
    } else {
        for (int l = tid; l < 8192; l += 256) {     // 2 arrays x 64 d x 64 px
            int a = l >> 12, dd = (l >> 6) & 63, px = l & 63;
            float v = ((const float*)(a ? xim : xre))[(long long)bt * 262144 + (long long)dd * 4096 + px0 + px];
            (a ? si : sr)[dd][px] = f2bu(v);
        }
    }
    __syncthreads();
    int px = tid & 63, part = tid >> 6;
    float s = 0.f, ss = 0.f;
    for (int d = part * 16; d < part * 16 + 16; d++) {
        float r = bu2f(sr[d][px]), q = bu2f(si[d][px]);
        s += r + q; ss += r * r + q * q;
    }
    red[0][part][px] = s; red[1][part][px] = ss;
    __syncthreads();
    if (tid < 64) {
        float S  = red[0][0][tid] + red[0][1][tid] + red[0][2][tid] + red[0][3][tid];
        float SS = red[1][0][tid] + red[1][1][tid] + red[1][2][tid] + red[1][3][tid];
        float m = S * (1.f / 128.f);
        mv[tid] = m;
        rv[tid] = rsqrtf(SS * (1.f / 128.f) - m * m + 1e-5f);
    }
    __syncthreads();
    unsigned short* xcb = (unsigned short*)(ws + XCBF);
    unsigned short* xnb = (unsigned short*)(ws + XNBF);
    long long pbase = ((long long)bt * 4096 + px0) * 128;
    for (int l = tid; l < 8192; l += 256) {
        int p2 = l >> 7, ch = l & 127, d = ch & 63;
        unsigned short raw = (ch < 64 ? sr : si)[d][p2];
        float v = bu2f(raw);
        xcb[pbase + p2 * 128 + ch] = raw;
        xnb[pbase + p2 * 128 + ch] = f2bu((v - mv[p2]) * rv[p2] * gb[ch] + gb[128 + ch]);
    }
}

// ---- stage B (fused B+C): 3x3 conv MFMA -> xupd; then eig MFMA + mean -------
__global__ __launch_bounds__(256) void kB_conv(const void* __restrict__ bc,
                                               float* __restrict__ ws) {
    __shared__ unsigned short xt[3][64][136] __attribute__((aligned(16)));
    bool bf = ws[FLAGO] != 0.f;
    int blk = blockIdx.x, bt = blk >> 6, h = blk & 63;
    int tid = threadIdx.x, lane = tid & 63, wv = tid >> 6;
    int m16 = lane & 15, quad = lane >> 4;
    const unsigned short* xnb = (const unsigned short*)(ws + XNBF);
    const unsigned short* wcp = (const unsigned short*)(ws + WCP);
    bhalf8 zero8 = {0, 0, 0, 0, 0, 0, 0, 0};
    for (int l = tid; l < 3072; l += 256) {   // 3 rows x 64 cols x 16 chunks
        int r = l >> 10, rem = l & 1023, col = rem >> 4, ck = rem & 15;
        int hr = h - 1 + r;
        bhalf8 v = zero8;
        if (hr >= 0 && hr < 64)
            v = *(const bhalf8*)&xnb[(((long long)bt * 4096 + hr * 64 + col) << 7) + ck * 8];
        *(bhalf8*)&xt[r][col][ck * 8] = v;
    }
    __syncthreads();
    floatx4 acc[4][2];
    #pragma unroll
    for (int mt = 0; mt < 4; mt++)
        #pragma unroll
        for (int nt = 0; nt < 2; nt++)
            acc[mt][nt] = (floatx4){0.f, 0.f, 0.f, 0.f};
    for (int tap = 0; tap < 9; tap++) {
        int dy = tap / 3, dx = tap - dy * 3;
        #pragma unroll
        for (int kc = 0; kc < 4; kc++) {
            bhalf8 bfr[2];
            #pragma unroll
            for (int nt = 0; nt < 2; nt++)
                bfr[nt] = *(const bhalf8*)&wcp[((((tap * 4 + kc) * 8) + (wv * 2 + nt)) * 64 + lane) * 8];
            #pragma unroll
            for (int mt = 0; mt < 4; mt++) {
                int col = mt * 16 + m16 + dx - 1;
                bhalf8 af = zero8;
                if (col >= 0 && col < 64)
                    af = *(const bhalf8*)&xt[dy][col][kc * 32 + quad * 8];
                acc[mt][0] = __builtin_amdgcn_mfma_f32_16x16x32_bf16(af, bfr[0], acc[mt][0], 0, 0, 0);
                acc[mt][1] = __builtin_amdgcn_mfma_f32_16x16x32_bf16(af, bfr[1], acc[mt][1], 0, 0, 0);
            }
        }
    }
    // epilogue: xupd = conv + xc + bc -> global xub AND LDS tile (reuse xt[0])
    __syncthreads();   // all waves done reading xt
    unsigned short (*At)[136] = (unsigned short(*)[136])&xt[0][0][0];
    const unsigned short* xcb = (const unsigned short*)(ws + XCBF);
    unsigned short* xub = (unsigned short*)(ws + XUBF);
    #pragma unroll
    for (int nt = 0; nt < 2; nt++) {
        int n = wv * 32 + nt * 16 + m16;
        float bcv = ld(bc, n, bf);
        #pragma unroll
        for (int mt = 0; mt < 4; mt++)
            #pragma unroll
            for (int r = 0; r < 4; r++) {
                int m = mt * 16 + quad * 4 + r;
                long long p = (long long)bt * 4096 + h * 64 + m;
                unsigned short u = f2bu(acc[mt][nt][r] + bu2f(xcb[p * 128 + n]) + bcv);
                xub[p * 128 + n] = u;
                At[m][n] = u;
            }
    }
    __syncthreads();
    // ---- fused eig GEMM: x_eig = xupd_tile @ WE -> BUFA bf16 + mean atomics --
    const unsigned short* wep = (const unsigned short*)(ws + WEP);
    long long px0 = (long long)blk * 64;
    floatx4 acce[4][2];
    #pragma unroll
    for (int mt = 0; mt < 4; mt++)
        #pragma unroll
        for (int nt = 0; nt < 2; nt++)
            acce[mt][nt] = (floatx4){0.f, 0.f, 0.f, 0.f};
    #pragma unroll
    for (int kc = 0; kc < 4; kc++) {
        bhalf8 bfr[2];
        #pragma unroll
        for (int nt = 0; nt < 2; nt++)
            bfr[nt] = *(const bhalf8*)&wep[(((kc * 8) + wv * 2 + nt) * 64 + lane) * 8];
        #pragma unroll
        for (int mt = 0; mt < 4; mt++) {
            bhalf8 af = *(const bhalf8*)&At[mt * 16 + m16][kc * 32 + quad * 8];
            acce[mt][0] = __builtin_amdgcn_mfma_f32_16x16x32_bf16(af, bfr[0], acce[mt][0], 0, 0, 0);
            acce[mt][1] = __builtin_amdgcn_mfma_f32_16x16x32_bf16(af, bfr[1], acce[mt][1], 0, 0, 0);
        }
    }
    unsigned short* xeb = (unsigned short*)(ws + BUFA);
    #pragma unroll
    for (int nt = 0; nt < 2; nt++) {
        int n = wv * 32 + nt * 16 + m16;
        float part = 0.f;
        #pragma unroll
        for (int mt = 0; mt < 4; mt++)
            #pragma unroll
            for (int r = 0; r < 4; r++) {
                int m = mt * 16 + quad * 4 + r;
                xeb[(px0 + m) * 128 + n] = f2bu(acce[mt][nt][r]);
                part += acce[mt][nt][r];
            }
        part += __shfl_xor(part, 16, 64);
        part += __shfl_xor(part, 32, 64);
        if (quad == 0) atomicAdd(ws + XMEAN + bt * 128 + n, part);
    }
}

// ---- stage D: flux recurrence, source, gate, op tables, flux_out ------------
__global__ __launch_bounds__(256) void kD_flux(const void* __restrict__ fxr, const void* __restrict__ fxi,
                                               const void* __restrict__ dtseq, const void* __restrict__ lamflux,
                                               const void* __restrict__ Wsr, const void* __restrict__ Wsi,
                                               const void* __restrict__ wgate, const void* __restrict__ bgate,
                                               const void* __restrict__ lamreraw, const void* __restrict__ lamim,
                                               float* __restrict__ ws, void* __restrict__ outv) {
    bool bfo = ws[FLAGO] != 0.f;
    int b = blockIdx.x;
    int tid = threadIdx.x;
    int d = tid & 63, g = tid >> 6;
    __shared__ float fr[64], fi[64], psr[4][64], psi[4][64];
    float lam_f = softplusf(ld(lamflux, d, bfo));
    float lre = -softplusf(ld(lamreraw, d, bfo));
    float lim = ld(lamim, d, bfo);
    float cr = 0.f, ci = 0.f;
    if (g == 0) { cr = ld(fxr, b * 64 + d, bfo); ci = ld(fxi, b * 64 + d, bfo); }
    float* tabs = ws + TABS;
    const float* xmean = ws + XMEAN;
    for (int t = 0; t < 16; t++) {
        float dt = ld(dtseq, b * 16 + t, bfo);
        int idx = b * 1024 + t * 64 + d;
        if (g == 0) {
            float A = expf(-lam_f * dt);
            float xr = xmean[(b * 16 + t) * 128 + d]      * (1.f / 4096.f) * dt;
            float xq = xmean[(b * 16 + t) * 128 + 64 + d] * (1.f / 4096.f) * dt;
            cr = A * cr + xr; ci = A * ci + xq;
            fr[d] = cr; fi[d] = ci;
        }
        __syncthreads();
        {
            float pr = 0.f, pi = 0.f;
            #pragma unroll
            for (int k = 0; k < 16; k++) {
                int d2 = g * 16 + k;
                float wr = ld(Wsr, d2 * 64 + d, bfo), wi = ld(Wsi, d2 * 64 + d, bfo);
                pr += fr[d2] * wr - fi[d2] * wi;
                pi += fr[d2] * wi + fi[d2] * wr;
            }
            psr[g][d] = pr; psi[g][d] = pi;
        }
        if (g == 1) {
            float od  = expf(lre * dt);
            float odr = od * cosf(lim * dt);
            float odi = od * sinf(lim * dt);
            tabs[3 * 2048 + idx] = odr; tabs[4 * 2048 + idx] = odi;
            float den = lre * lre + lim * lim;
            float tr = odr - 1.f;
            tabs[5 * 2048 + idx] = (tr * lre + odi * lim) / den;
            tabs[6 * 2048 + idx] = (odi * lre - tr * lim) / den;
        }
        __syncthreads();
        if (g == 0) {
            float sr = psr[0][d] + psr[1][d] + psr[2][d] + psr[3][d];
            float si2 = psi[0][d] + psi[1][d] + psi[2][d] + psi[3][d];
            tabs[1 * 2048 + idx] = sr; tabs[2 * 2048 + idx] = si2;
            tabs[0 * 2048 + idx] = 1.f / (1.f + expf(-(cr * ld(wgate, d, bfo) + ld(bgate, d, bfo))));
            if (t == 15) {
                if (bfo) {
                    bf16* ob = (bf16*)outv;
                    ob[FOUT + (b * 64 + d) * 2]     = f2b(cr);
                    ob[FOUT + (b * 64 + d) * 2 + 1] = f2b(ci);
                } else {
                    float* of = (float*)outv;
                    of[FOUT + (b * 64 + d) * 2]     = cr;
                    of[FOUT + (b * 64 + d) * 2 + 1] = ci;
                }
            }
        }
    }
}

// ---- stage E: time recurrence, 2 channels/thread ----------------------------
__global__ __launch_bounds__(256) void kE_scan(const void* __restrict__ hre,
                                               const void* __restrict__ him,
                                               float* __restrict__ ws, void* __restrict__ outv) {
    __shared__ float tab[7][16][64];
    bool bfo = ws[FLAGO] != 0.f;
    int tid = threadIdx.x;
    long long G = (long long)blockIdx.x * 256 + tid;
    int d0 = (int)(G & 31) * 2;
    int pixg = (int)(G >> 5);          // 0..8191
    int pix = pixg & 4095;
    int b = pixg >> 12;
    const float* tabs = ws + TABS;
    for (int l = tid; l < 7 * 1024; l += 256) {
        int a = l >> 10, idx = l & 1023;
        ((float*)tab)[l] = tabs[a * 2048 + b * 1024 + idx];
    }
    __syncthreads();
    long long hidx = ((long long)b * 4096 + pix) * 64 + d0;
    float cr0, ci0, cr1, ci1;
    if (bfo) {
        unsigned int r2 = *(const unsigned int*)&((const unsigned short*)hre)[hidx];
        unsigned int i2 = *(const unsigned int*)&((const unsigned short*)him)[hidx];
        cr0 = bu2f((unsigned short)(r2 & 0xffff)); cr1 = bu2f((unsigned short)(r2 >> 16));
        ci0 = bu2f((unsigned short)(i2 & 0xffff)); ci1 = bu2f((unsigned short)(i2 >> 16));
    } else {
        float2 r2 = *(const float2*)((const float*)hre + hidx);
        float2 i2 = *(const float2*)((const float*)him + hidx);
        cr0 = r2.x; cr1 = r2.y; ci0 = i2.x; ci1 = i2.y;
    }
    const unsigned short* xe = (const unsigned short*)(ws + BUFA);
    unsigned short* ub = (unsigned short*)(ws + XCBF);
    for (int t = 0; t < 16; t++) {
        long long base = ((long long)((b * 16 + t) * 4096 + pix)) * 128 + d0;
        unsigned int xr2 = *(const unsigned int*)&xe[base];
        unsigned int xi2 = *(const unsigned int*)&xe[base + 64];
        float2 gt2  = *(const float2*)&tab[0][t][d0];
        float2 sr2  = *(const float2*)&tab[1][t][d0];
        float2 si2  = *(const float2*)&tab[2][t][d0];
        float2 odr2 = *(const float2*)&tab[3][t][d0];
        float2 odi2 = *(const float2*)&tab[4][t][d0];
        float2 ofr2 = *(const float2*)&tab[5][t][d0];
        float2 ofi2 = *(const float2*)&tab[6][t][d0];
        {
            float xr = bu2f((unsigned short)(xr2 & 0xffff));
            float xi = bu2f((unsigned short)(xi2 & 0xffff));
            float fre = xr * gt2.x + sr2.x * (1.f - gt2.x);
            float fim = xi * gt2.x + si2.x * (1.f - gt2.x);
            float ure = fre * ofr2.x - fim * ofi2.x;
            float uim = fre * ofi2.x + fim * ofr2.x;
            float n0 = odr2.x * cr0 - odi2.x * ci0 + ure;
            float n1 = odr2.x * ci0 + odi2.x * cr0 + uim;
            cr0 = n0; ci0 = n1;
        }
        {
            float xr = bu2f((unsigned short)(xr2 >> 16));
            float xi = bu2f((unsigned short)(xi2 >> 16));
            float fre = xr * gt2.y + sr2.y * (1.f - gt2.y);
            float fim = xi * gt2.y + si2.y * (1.f - gt2.y);
            float ure = fre * ofr2.y - fim * ofi2.y;
            float uim = fre * ofi2.y + fim * ofr2.y;
            float n0 = odr2.y * cr1 - odi2.y * ci1 + ure;
            float n1 = odr2.y * ci1 + odi2.y * cr1 + uim;
            cr1 = n0; ci1 = n1;
        }
        *(unsigned int*)&ub[base]      = (unsigned int)f2bu(cr0) | ((unsigned int)f2bu(cr1) << 16);
        *(unsigned int*)&ub[base + 64] = (unsigned int)f2bu(ci0) | ((unsigned int)f2bu(ci1) << 16);
    }
    if (bfo) {
        uint2 hv;
        hv.x = (unsigned int)f2bu(cr0) | ((unsigned int)f2bu(ci0) << 16);
        hv.y = (unsigned int)f2bu(cr1) | ((unsigned int)f2bu(ci1) << 16);
        *(uint2*)((unsigned short*)outv + HOUT + 2 * hidx) = hv;
    } else {
        float4 hv; hv.x = cr0; hv.y = ci0; hv.z = cr1; hv.w = ci1;
        *(float4*)((float*)outv + HOUT + 2 * hidx) = hv;
    }
}

// ---- stage F fused: dec MFMA + LN + MLP MFMA + z epilogue -------------------
// 32-px tile. decoded/dn stay in LDS; LN stats from f32 accumulators (in-wave
// shfl reduce) so numerics match the old kF1 exactly. LDS pool: u-tile (8.7K)
// unioned with h1f (16K); total 36.6KB -> 4 blocks/CU.
__global__ __launch_bounds__(256, 4) void kMLP(const void* __restrict__ gt_,
                                               const void* __restrict__ bt_,
                                               const void* __restrict__ b1v,
                                               const void* __restrict__ b2v,
                                               float* __restrict__ ws, void* __restrict__ outv) {
    __shared__ unsigned char POOL[16384] __attribute__((aligned(16)));   // UA | h1f
    __shared__ unsigned short Dt[32][136] __attribute__((aligned(16)));  // decoded bf16
    __shared__ unsigned short A1[32][136] __attribute__((aligned(16)));  // dn bf16 -> C
    __shared__ float gbt[256];
    __shared__ float gb2[128];
    __shared__ float psS[4][32], psQ[4][32];
    __shared__ float mvv[32], rvv[32];
    unsigned short (*UA)[136] = (unsigned short(*)[136])POOL;            // [32][136]
    unsigned short (*h1f)[2][64][8] = (unsigned short(*)[2][64][8])POOL; // [8][2][64][8]
    bool bf = ws[FLAGO] != 0.f;
    long long px0 = (long long)blockIdx.x * 32;
    int tid = threadIdx.x, lane = tid & 63, wv = tid >> 6;
    int m16 = lane & 15, quad = lane >> 4;
    gbt[tid] = (tid < 128) ? ld(gt_, tid, bf) : ld(bt_, tid - 128, bf);
    if (tid < 128) gb2[tid] = ld(b2v, tid, bf);
    const unsigned short* uo = (const unsigned short*)(ws + XCBF);
    for (int l = tid; l < 512; l += 256) {
        int p2 = l >> 4, ck = l & 15;
        *(bhalf8*)&UA[p2][ck * 8] = *(const bhalf8*)&uo[(px0 + p2) * 128 + ck * 8];
    }
    __syncthreads();
    // ---- dec GEMM: decoded = u_tile @ WD ----
    const unsigned short* wdp = (const unsigned short*)(ws + WDP);
    floatx4 accd[2][2];
    #pragma unroll
    for (int mt = 0; mt < 2; mt++)
        #pragma unroll
        for (int nt = 0; nt < 2; nt++)
            accd[mt][nt] = (floatx4){0.f, 0.f, 0.f, 0.f};
    #pragma unroll
    for (int kc = 0; kc < 4; kc++) {
        bhalf8 bfr0 = *(const bhalf8*)&wdp[(((kc * 8) + wv * 2 + 0) * 64 + lane) * 8];
        bhalf8 bfr1 = *(const bhalf8*)&wdp[(((kc * 8) + wv * 2 + 1) * 64 + lane) * 8];
        bhalf8 af0 = *(const bhalf8*)&UA[m16][kc * 32 + quad * 8];
        bhalf8 af1 = *(const bhalf8*)&UA[16 + m16][kc * 32 + quad * 8];
        accd[0][0] = __builtin_amdgcn_mfma_f32_16x16x32_bf16(af0, bfr0, accd[0][0], 0, 0, 0);
        accd[0][1] = __builtin_amdgcn_mfma_f32_16x16x32_bf16(af0, bfr1, accd[0][1], 0, 0, 0);
        accd[1][0] = __builtin_amdgcn_mfma_f32_16x16x32_bf16(af1, bfr0, accd[1][0], 0, 0, 0);
        accd[1][1] = __builtin_amdgcn_mfma_f32_16x16x32_bf16(af1, bfr1, accd[1][1], 0, 0, 0);
    }
    // ---- Dt write + per-wave f32 LN partial sums (shfl over m16 lanes) ----
    #pragma unroll
    for (int mt = 0; mt < 2; mt++)
        #pragma unroll
        for (int r = 0; r < 4; r++) {
            int mrow = mt * 16 + quad * 4 + r;
            float a0 = accd[mt][0][r], a1 = accd[mt][1][r];
            Dt[mrow][wv * 32 + m16]      = f2bu(a0);
            Dt[mrow][wv * 32 + 16 + m16] = f2bu(a1);
            float s = a0 + a1, q = a0 * a0 + a1 * a1;
            #pragma unroll
            for (int msk = 1; msk <= 8; msk <<= 1) {
                s += __shfl_xor(s, msk, 64);
                q += __shfl_xor(q, msk, 64);
            }
            if (m16 == 0) { psS[wv][mrow] = s; psQ[wv][mrow] = q; }
        }
    __syncthreads();
    if (tid < 32) {
        float S = psS[0][tid] + psS[1][tid] + psS[2][tid] + psS[3][tid];
        float Q = psQ[0][tid] + psQ[1][tid] + psQ[2][tid] + psQ[3][tid];
        float m = S * (1.f / 128.f);
        mvv[tid] = m;
        rvv[tid] = rsqrtf(Q * (1.f / 128.f) - m * m + 1e-5f);
    }
    __syncthreads();
    // ---- dn (LN of decoded, f32 fidelity) -> A1 ----
    #pragma unroll
    for (int mt = 0; mt < 2; mt++)
        #pragma unroll
        for (int r = 0; r < 4; r++) {
            int mrow = mt * 16 + quad * 4 + r;
            float mu = mvv[mrow], rs = rvv[mrow];
            #pragma unroll
            for (int nt = 0; nt < 2; nt++) {
                int n = wv * 32 + nt * 16 + m16;
                A1[mrow][n] = f2bu((accd[mt][nt][r] - mu) * rs * gbt[n] + gbt[128 + n]);
            }
        }
    __syncthreads();
    // ---- MLP: two-phase GEMM1 -> gelu -> h1f (A-frag layout) -> GEMM2 ------
    const unsigned short* w1p = (const unsigned short*)(ws + W1P);
    const unsigned short* w2p = (const unsigned short*)(ws + W2P);
    floatx4 acc2[2][2];
    #pragma unroll
    for (int mt = 0; mt < 2; mt++)
        #pragma unroll
        for (int nt = 0; nt < 2; nt++)
            acc2[mt][nt] = (floatx4){0.f, 0.f, 0.f, 0.f};
    #pragma unroll
    for (int ph = 0; ph < 2; ph++) {
        floatx4 acc1[2][4];
        #pragma unroll
        for (int mt = 0; mt < 2; mt++)
            #pragma unroll
            for (int nt4 = 0; nt4 < 4; nt4++)
                acc1[mt][nt4] = (floatx4){0.f, 0.f, 0.f, 0.f};
        #pragma unroll
        for (int kc = 0; kc < 4; kc++) {
            bhalf8 af0 = *(const bhalf8*)&A1[m16][kc * 32 + quad * 8];
            bhalf8 af1 = *(const bhalf8*)&A1[16 + m16][kc * 32 + quad * 8];
            #pragma unroll
            for (int nt4 = 0; nt4 < 4; nt4++) {
                int nt = ph * 4 + nt4;
                bhalf8 bfr = *(const bhalf8*)&w1p[(((kc * 32) + wv * 8 + nt) * 64 + lane) * 8];
                acc1[0][nt4] = __builtin_amdgcn_mfma_f32_16x16x32_bf16(af0, bfr, acc1[0][nt4], 0, 0, 0);
                acc1[1][nt4] = __builtin_amdgcn_mfma_f32_16x16x32_bf16(af1, bfr, acc1[1][nt4], 0, 0, 0);
            }
        }
        if (ph == 0) __syncthreads();   // UA fully consumed before h1f overwrite
        #pragma unroll
        for (int nt4 = 0; nt4 < 4; nt4++) {
            int nt = ph * 4 + nt4;
            int n = (wv * 8 + nt) * 16 + m16;
            float b1f = ld(b1v, n, bf);
            int qp = ((nt * 2) + (m16 >> 3)) & 3;
            int slot = wv * 2 + (nt4 >> 1);
            int j = m16 & 7;
            #pragma unroll
            for (int mt = 0; mt < 2; mt++)
                #pragma unroll
                for (int r = 0; r < 4; r++)
                    h1f[slot][mt][qp * 16 + quad * 4 + r][j] =
                        f2bu(geluf(acc1[mt][nt4][r] + b1f));
        }
        __syncthreads();
        #pragma unroll
        for (int s = 0; s < 8; s++) {
            int kc2g = (s >> 1) * 4 + (s & 1) + ph * 2;   // k-block index in w2p
            bhalf8 a0 = *(const bhalf8*)&h1f[s][0][lane][0];
            bhalf8 a1 = *(const bhalf8*)&h1f[s][1][lane][0];
            #pragma unroll
            for (int nt = 0; nt < 2; nt++) {
                bhalf8 bfr = *(const bhalf8*)&w2p[(((kc2g * 8) + wv * 2 + nt) * 64 + lane) * 8];
                acc2[0][nt] = __builtin_amdgcn_mfma_f32_16x16x32_bf16(a0, bfr, acc2[0][nt], 0, 0, 0);
                acc2[1][nt] = __builtin_amdgcn_mfma_f32_16x16x32_bf16(a1, bfr, acc2[1][nt], 0, 0, 0);
            }
        }
        if (ph == 0) __syncthreads();   // h1f consumed before phase-1 overwrite
    }
    // ---- C round-trip through A1 for pixel-major epilogue ----
    #pragma unroll
    for (int nt = 0; nt < 2; nt++) {
        int n = wv * 32 + nt * 16 + m16;
        #pragma unroll
        for (int mt = 0; mt < 2; mt++)
            #pragma unroll
            for (int r = 0; r < 4; r++)
                A1[mt * 16 + quad * 4 + r][n] = f2bu(acc2[mt][nt][r]);
    }
    __syncthreads();
    {
        const unsigned short* xub = (const unsigned short*)(ws + XUBF);
        int pxl = tid >> 3, dc = (tid & 7) * 8;
        long long p = px0 + pxl;
        bhalf8 cre = *(const bhalf8*)&A1[pxl][dc];
        bhalf8 cim = *(const bhalf8*)&A1[pxl][64 + dc];
        bhalf8 xr8 = *(const bhalf8*)&xub[p * 128 + dc];
        bhalf8 xi8 = *(const bhalf8*)&xub[p * 128 + 64 + dc];
        bhalf8 dr8 = *(const bhalf8*)&Dt[pxl][dc];
        bhalf8 di8 = *(const bhalf8*)&Dt[pxl][64 + dc];
        float zr[8], zi[8];
        #pragma unroll
        for (int k = 0; k < 8; k++) {
            zr[k] = bu2f((unsigned short)cre[k]) + gb2[dc + k]
                  + bu2f((unsigned short)xr8[k]) + bu2f((unsigned short)dr8[k]);
            zi[k] = bu2f((unsigned short)cim[k]) + gb2[64 + dc + k]
                  + bu2f((unsigned short)xi8[k]) + bu2f((unsigned short)di8[k]);
        }
        if (bf) {
            unsigned short o[16];
            #pragma unroll
            for (int k = 0; k < 8; k++) { o[2 * k] = f2bu(zr[k]); o[2 * k + 1] = f2bu(zi[k]); }
            unsigned short* ob = (unsigned short*)outv;
            *(bhalf8*)&ob[ZOUT + p * 128 + 2 * dc]     = *(bhalf8*)&o[0];
            *(bhalf8*)&ob[ZOUT + p * 128 + 2 * dc + 8] = *(bhalf8*)&o[8];
        } else {
            float* of = (float*)outv + ZOUT + p * 128 + 2 * dc;
            #pragma unroll
            for (int k = 0; k < 8; k++) { of[2 * k] = zr[k]; of[2 * k + 1] = zi[k]; }
        }
    }
}

extern "C" void kernel_launch(void* const* d_in, const int* in_sizes, int n_in,
                              void* d_out, int out_size, void* d_ws, size_t ws_size,
                              hipStream_t stream) {
    const void* x_re  = d_in[0];
    const void* x_im  = d_in[1];
    const void* h_re  = d_in[2];
    const void* h_im  = d_in[3];
    const void* fl_re = d_in[4];
    const void* fl_im = d_in[5];
    const void* dtseq = d_in[6];
    const void* g_s   = d_in[7];
    const void* b_s   = d_in[8];
    const void* Wc    = d_in[9];
    const void* bc    = d_in[10];
    const void* g_t   = d_in[11];
    const void* b_t   = d_in[12];
    const void* E_re  = d_in[13];
    const void* E_im  = d_in[14];
    const void* De_re = d_in[15];
    const void* De_im = d_in[16];
    const void* lamfl = d_in[17];
    const void* Ws_re = d_in[18];
    const void* Ws_im = d_in[19];
    const void* wgate = d_in[20];
    const void* bgate = d_in[21];
    const void* lamrr = d_in[22];
    const void* lamim = d_in[23];
    const void* W1    = d_in[24];
    const void* b1    = d_in[25];
    const void* W2    = d_in[26];
    const void* b2    = d_in[27];
    float* ws = (float*)d_ws;

    hipMemsetAsync((char*)d_ws + XMEAN * sizeof(float), 0, 4096 * sizeof(float), stream);
    k_detect<<<1, 64, 0, stream>>>((const unsigned short*)x_re, ws);
    k_convert<<<1216, 256, 0, stream>>>(Wc, W1, W2, E_re, E_im, De_re, De_im, ws);
    kA_ln<<<2048, 256, 0, stream>>>(x_re, x_im, g_s, b_s, ws);
    kB_conv<<<2048, 256, 0, stream>>>(bc, ws);
    kD_flux<<<2, 256, 0, stream>>>(fl_re, fl_im, dtseq, lamfl, Ws_re, Ws_im,
                                   wgate, bgate, lamrr, lamim, ws, d_out);
    kE_scan<<<1024, 256, 0, stream>>>(h_re, h_im, ws, d_out);
    kMLP<<<4096, 256, 0, stream>>>(g_t, b_t, b1, b2, ws, d_out);
}